// Round 8
// baseline (232.540 us; speedup 1.0000x reference)
//
#include <hip/hip_runtime.h>

// MaskedAttentionLayer B=4,S=2048,E=1024,H=16,HD=64; fp32 io, bf16 MFMA.
// R8: flash_attn rewritten k-parallel-across-waves: unnormalized exp2 softmax
// makes O,l additive over k, so each wave processes disjoint 64x64 k-tiles
// independently -> ZERO barriers in the hot loop. K/V frags direct from global
// (no redundancy: each wave reads distinct K rows; V^T [b,h,d,s] rows).
// O^T = V^T @ P with P via wave-private LDS. Cross-wave O/l reduction at
// epilogue (3 barriers per q-tile, LDS reused). qkv_gemm/cvt unchanged.

typedef __bf16 bf16x8 __attribute__((ext_vector_type(8)));
typedef __bf16 bf16x4 __attribute__((ext_vector_type(4)));
typedef float f32x4 __attribute__((ext_vector_type(4)));
typedef unsigned short us8 __attribute__((ext_vector_type(8)));
typedef unsigned short us4 __attribute__((ext_vector_type(4)));

#define Bb 4
#define Ss 2048
#define Ee 1024
#define Hh 16
#define HD 64

#if __has_builtin(__builtin_amdgcn_exp2f)
#define EXP2(x) __builtin_amdgcn_exp2f(x)
#else
#define EXP2(x) exp2f(x)
#endif

__device__ __forceinline__ unsigned short f2bf(float f) {
  union { float f; unsigned u; } v; v.f = f;
  unsigned u = v.u;
  u += 0x7fffu + ((u >> 16) & 1u);   // RNE
  return (unsigned short)(u >> 16);
}

__device__ __forceinline__ void gl_lds16(const void* g, void* l) {
  __builtin_amdgcn_global_load_lds((const __attribute__((address_space(1))) void*)g,
                                   (__attribute__((address_space(3))) void*)l, 16, 0, 0);
}

// one kernel for all fp32->bf16 converts (x, Wq, Wk, Wv)
__global__ __launch_bounds__(256) void cvt_all(const float* __restrict__ x,
                                               const float* __restrict__ wq,
                                               const float* __restrict__ wk,
                                               const float* __restrict__ wv,
                                               unsigned short* __restrict__ xb,
                                               unsigned short* __restrict__ wb) {
  int i = blockIdx.x * 256 + threadIdx.x;   // float4 index, total 2883584
  const float* src; unsigned short* dst; int idx;
  if (i < 2097152)      { src = x;  dst = xb;                idx = i; }
  else if (i < 2359296) { src = wq; dst = wb;                idx = i - 2097152; }
  else if (i < 2621440) { src = wk; dst = wb + 1048576;      idx = i - 2359296; }
  else                  { src = wv; dst = wb + 2 * 1048576;  idx = i - 2621440; }
  float4 f = ((const float4*)src)[idx];
  us4 o = { f2bf(f.x), f2bf(f.y), f2bf(f.z), f2bf(f.w) };
  ((us4*)dst)[idx] = o;
}

// C[m,n] = sum_e X[m,e] W[n,e] + bias[n].  128x128 tile, BK=64 (2x32 panels).
// z=0 (Q): [b,h,s,d] scaled by 0.125*log2e.  z=1 (K): [b,h,s,d].  z=2 (V): [b,h,d,s].
__global__ __launch_bounds__(256, 3) void qkv_gemm(const unsigned short* __restrict__ xb,
                                                   const unsigned short* __restrict__ wb_all,
                                                   const float* __restrict__ bq,
                                                   const float* __restrict__ bk,
                                                   const float* __restrict__ bv,
                                                   unsigned short* __restrict__ qkv) {
  const int z = blockIdx.z;
  const unsigned short* wb = wb_all + (size_t)z * (Ee * Ee);
  const float* bias = (z == 0) ? bq : (z == 1) ? bk : bv;
  unsigned short* outb = qkv + (size_t)z * (Bb * Ss * Ee);
  const float osc = (z == 0) ? 0.180336880f : 1.0f;   // 0.125 * log2(e)

  __shared__ unsigned short SMEM[16384];
  unsigned short* As = SMEM;
  unsigned short* Bs = SMEM + 8192;

  const int t = threadIdx.x;
  const int wave = t >> 6, lane = t & 63, quad = lane >> 4, ln = lane & 15;
  const int wm = wave & 1, wn = wave >> 1;
  const int m0 = blockIdx.x * 128, n0 = blockIdx.y * 128;

  const int srow = t >> 2;
  const int scol = (t & 3) * 8;

  f32x4 acc[4][4] = {};

  const unsigned short* ga = xb + (size_t)(m0 + srow) * Ee + scol;
  const unsigned short* gb = wb + (size_t)(n0 + srow) * Ee + scol;
  unsigned short* la = &As[t * 8];
  unsigned short* lb = &Bs[t * 8];

  for (int k0 = 0; k0 < Ee; k0 += 64) {
    __syncthreads();
    gl_lds16(ga + k0,                la);
    gl_lds16(ga + k0 + 64 * Ee,      la + 64 * 32);
    gl_lds16(gb + k0,                lb);
    gl_lds16(gb + k0 + 64 * Ee,      lb + 64 * 32);
    gl_lds16(ga + k0 + 32,           la + 4096);
    gl_lds16(ga + k0 + 32 + 64 * Ee, la + 4096 + 64 * 32);
    gl_lds16(gb + k0 + 32,           lb + 4096);
    gl_lds16(gb + k0 + 32 + 64 * Ee, lb + 4096 + 64 * 32);
    __syncthreads();
#pragma unroll
    for (int p = 0; p < 2; ++p) {
      bf16x8 af[4], bfr[4];
#pragma unroll
      for (int i = 0; i < 4; ++i)
        af[i] = *(const bf16x8*)&As[p * 4096 + (wm * 64 + i * 16 + ln) * 32 + quad * 8];
#pragma unroll
      for (int j = 0; j < 4; ++j)
        bfr[j] = *(const bf16x8*)&Bs[p * 4096 + (wn * 64 + j * 16 + ln) * 32 + quad * 8];
#pragma unroll
      for (int i = 0; i < 4; ++i)
#pragma unroll
        for (int j = 0; j < 4; ++j)
          acc[i][j] = __builtin_amdgcn_mfma_f32_16x16x32_bf16(af[i], bfr[j], acc[i][j], 0, 0, 0);
    }
  }

  float biasj[4];
#pragma unroll
  for (int j = 0; j < 4; ++j) biasj[j] = bias[n0 + wn * 64 + j * 16 + ln];

  if (z != 2) {
#pragma unroll
    for (int i = 0; i < 4; ++i)
#pragma unroll
      for (int j = 0; j < 4; ++j)
#pragma unroll
        for (int r = 0; r < 4; ++r) {
          int m = m0 + wm * 64 + i * 16 + quad * 4 + r;
          int n = n0 + wn * 64 + j * 16 + ln;
          int b_ = m >> 11, s = m & 2047;
          int h = n >> 6, d = n & 63;
          outb[(((size_t)b_ * Hh + h) * Ss + s) * HD + d] = f2bf((acc[i][j][r] + biasj[j]) * osc);
        }
  } else {
    for (int half = 0; half < 2; ++half) {
      __syncthreads();
      if (wm == half) {
#pragma unroll
        for (int i = 0; i < 4; ++i)
#pragma unroll
          for (int j = 0; j < 4; ++j)
#pragma unroll
            for (int r = 0; r < 4; ++r) {
              int mr = i * 16 + quad * 4 + r;
              int nc = wn * 64 + j * 16 + ln;
              SMEM[nc * 72 + mr] = f2bf(acc[i][j][r] + biasj[j]);
            }
      }
      __syncthreads();
      int nr = t >> 1;
      int n = n0 + nr;
      int h = n >> 6, d = n & 63;
      int mbase = m0 + half * 64 + (t & 1) * 32;
      int b_ = mbase >> 11;
#pragma unroll
      for (int q = 0; q < 4; ++q) {
        int s = (mbase & 2047) + q * 8;
        us8 vdat = *(const us8*)&SMEM[nr * 72 + (t & 1) * 32 + q * 8];
        *(us8*)&outb[(((size_t)b_ * Hh + h) * HD + d) * Ss + s] = vdat;
      }
    }
  }
}

// Flash attention, causal, k-parallel waves, max-free exp2 softmax.
// grid = 1024 (64 bh x 16 pairs {31-p, p}); block = one 64-row q-tile per phase.
// Wave w handles k-tiles {w, w+4, ...} independently (no barriers in loop);
// partial O^T (64d x 64q) + l summed across waves in epilogue.
__global__ __launch_bounds__(256, 2) void flash_attn(const unsigned short* __restrict__ qkv,
                                                     float* __restrict__ out) {
  const int id = blockIdx.x;
  const int bh = id & 63;
  const int p = id >> 6;             // 0..15
  const int b_ = bh >> 4, h = bh & 15;

  const unsigned short* qb  = qkv + (size_t)bh * (Ss * HD);
  const unsigned short* kb  = qkv + (size_t)(64 + bh) * (Ss * HD);
  const unsigned short* vtb = qkv + (size_t)(128 + bh) * (Ss * HD);  // [d][s]

  __shared__ char SM[36864];           // Ps: 4 waves x [64][72] bf16
  __bf16* Ps   = (__bf16*)SM;          // epilogue alias: bufA/bufB f32 [64][68]
  float*  bufA = (float*)SM;
  float*  bufB = (float*)(SM + 17408);
  __shared__ float Lbuf[4][64];

  const int t = threadIdx.x;
  const int wave = t >> 6, lane = t & 63, quad = lane >> 4, ln = lane & 15;
  __bf16* Pw = Ps + wave * (64 * 72);

  bf16x8 onef;
#pragma unroll
  for (int j = 0; j < 8; ++j) onef[j] = (__bf16)1.0f;

  const int qts[2] = { 31 - p, p };

  for (int ph = 0; ph < 2; ++ph) {
    const int qt = qts[ph];
    const int q0 = qt * 64;

    // Q B-frags for all 64 q-rows of the tile
    bf16x8 qf[4][2];
#pragma unroll
    for (int gb = 0; gb < 4; ++gb)
#pragma unroll
      for (int ks = 0; ks < 2; ++ks)
        qf[gb][ks] = *(const bf16x8*)(qb + (size_t)(q0 + gb * 16 + ln) * HD + ks * 32 + quad * 8);

    f32x4 o[4][4] = {};   // O^T[d-group gd][q-group gb]
    f32x4 l4[4]  = {};    // l per q-group (ones-A MFMA; all r identical)

    for (int kt = wave; kt <= qt; kt += 4) {
      const unsigned short* kbase = kb + (size_t)kt * (64 * HD);
      bf16x8 kf[4][2], vf[4][2];
#pragma unroll
      for (int ga = 0; ga < 4; ++ga)
#pragma unroll
        for (int ks = 0; ks < 2; ++ks)
          kf[ga][ks] = *(const bf16x8*)(kbase + (size_t)(ga * 16 + ln) * HD + ks * 32 + quad * 8);
#pragma unroll
      for (int gd = 0; gd < 4; ++gd)
#pragma unroll
        for (int ks = 0; ks < 2; ++ks)
          vf[gd][ks] = *(const bf16x8*)(vtb + (size_t)(gd * 16 + ln) * Ss + kt * 64 + ks * 32 + quad * 8);
      const bool diag = (kt == qt);

#pragma unroll
      for (int gb = 0; gb < 4; ++gb) {
        // S^T[kcol][qrow-group gb] = K Q^T
        f32x4 s[4] = {};
#pragma unroll
        for (int ga = 0; ga < 4; ++ga)
#pragma unroll
          for (int ks = 0; ks < 2; ++ks)
            s[ga] = __builtin_amdgcn_mfma_f32_16x16x32_bf16(kf[ga][ks], qf[gb][ks], s[ga], 0, 0, 0);

        // p = exp2(s) (0 where masked), pack to wave-private Ps[qrow][kcol]
#pragma unroll
        for (int ga = 0; ga < 4; ++ga) {
          float pv[4];
#pragma unroll
          for (int r = 0; r < 4; ++r) {
            float e = EXP2(s[ga][r]);
            pv[r] = (diag && (ga * 16 + quad * 4 + r > gb * 16 + ln)) ? 0.f : e;
          }
          bf16x4 pk = { (__bf16)pv[0], (__bf16)pv[1], (__bf16)pv[2], (__bf16)pv[3] };
          *(bf16x4*)&Pw[(gb * 16 + ln) * 72 + ga * 16 + quad * 4] = pk;
        }
        bf16x8 pf0 = *(const bf16x8*)&Pw[(gb * 16 + ln) * 72 + quad * 8];
        bf16x8 pf1 = *(const bf16x8*)&Pw[(gb * 16 + ln) * 72 + 32 + quad * 8];

        // l += ones @ P   (C[n=qrow], every m-row identical)
        l4[gb] = __builtin_amdgcn_mfma_f32_16x16x32_bf16(onef, pf0, l4[gb], 0, 0, 0);
        l4[gb] = __builtin_amdgcn_mfma_f32_16x16x32_bf16(onef, pf1, l4[gb], 0, 0, 0);

        // O^T += V^T @ P
#pragma unroll
        for (int gd = 0; gd < 4; ++gd) {
          o[gd][gb] = __builtin_amdgcn_mfma_f32_16x16x32_bf16(vf[gd][0], pf0, o[gd][gb], 0, 0, 0);
          o[gd][gb] = __builtin_amdgcn_mfma_f32_16x16x32_bf16(vf[gd][1], pf1, o[gd][gb], 0, 0, 0);
        }
      }
    }

    // ---- cross-wave reduction (O^T partials + l partials) ----
    if (quad == 0) {
#pragma unroll
      for (int gb = 0; gb < 4; ++gb) Lbuf[wave][gb * 16 + ln] = l4[gb][0];
    }
    __syncthreads();              // all waves done with Ps reads + k-loop
    if (wave == 0) {
#pragma unroll
      for (int gd = 0; gd < 4; ++gd)
#pragma unroll
        for (int gb = 0; gb < 4; ++gb)
#pragma unroll
          for (int r = 0; r < 4; ++r)
            bufA[(gd * 16 + quad * 4 + r) * 68 + gb * 16 + ln] = o[gd][gb][r];
    } else if (wave == 1) {
#pragma unroll
      for (int gd = 0; gd < 4; ++gd)
#pragma unroll
        for (int gb = 0; gb < 4; ++gb)
#pragma unroll
          for (int r = 0; r < 4; ++r)
            bufB[(gd * 16 + quad * 4 + r) * 68 + gb * 16 + ln] = o[gd][gb][r];
    }
    __syncthreads();
    if (wave == 2) {
#pragma unroll
      for (int gd = 0; gd < 4; ++gd)
#pragma unroll
        for (int gb = 0; gb < 4; ++gb)
#pragma unroll
          for (int r = 0; r < 4; ++r)
            bufA[(gd * 16 + quad * 4 + r) * 68 + gb * 16 + ln] += o[gd][gb][r];
    } else if (wave == 3) {
#pragma unroll
      for (int gd = 0; gd < 4; ++gd)
#pragma unroll
        for (int gb = 0; gb < 4; ++gb)
#pragma unroll
          for (int r = 0; r < 4; ++r)
            bufB[(gd * 16 + quad * 4 + r) * 68 + gb * 16 + ln] += o[gd][gb][r];
    }
    __syncthreads();
    {
      const int q = t >> 2;
      const int dbase = (t & 3) * 16;
      float ltot = Lbuf[0][q] + Lbuf[1][q] + Lbuf[2][q] + Lbuf[3][q];
      float linv = 1.0f / ltot;
      float* op = out + ((size_t)b_ * Ss + q0 + q) * Ee + h * HD + dbase;
#pragma unroll
      for (int c = 0; c < 4; ++c) {
        int d = dbase + c * 4;
        float4 vv;
        vv.x = (bufA[(d + 0) * 68 + q] + bufB[(d + 0) * 68 + q]) * linv;
        vv.y = (bufA[(d + 1) * 68 + q] + bufB[(d + 1) * 68 + q]) * linv;
        vv.z = (bufA[(d + 2) * 68 + q] + bufB[(d + 2) * 68 + q]) * linv;
        vv.w = (bufA[(d + 3) * 68 + q] + bufB[(d + 3) * 68 + q]) * linv;
        ((float4*)op)[c] = vv;
      }
    }
    __syncthreads();   // protect aliased LDS before next phase's Ps writes
  }
}

extern "C" void kernel_launch(void* const* d_in, const int* in_sizes, int n_in,
                              void* d_out, int out_size, void* d_ws, size_t ws_size,
                              hipStream_t stream) {
  const float* x  = (const float*)d_in[0];
  const float* Wq = (const float*)d_in[1];
  const float* bq = (const float*)d_in[2];
  const float* Wk = (const float*)d_in[3];
  const float* bk = (const float*)d_in[4];
  const float* Wv = (const float*)d_in[5];
  const float* bv = (const float*)d_in[6];
  float* out = (float*)d_out;

  unsigned short* ws  = (unsigned short*)d_ws;
  unsigned short* xb  = ws;                                   // 8388608
  unsigned short* wb  = ws + 8388608;                         // 3 * 1048576
  unsigned short* qkv = ws + 8388608 + 3 * 1048576;           // 3 * 8388608

  cvt_all<<<11264, 256, 0, stream>>>(x, Wq, Wk, Wv, xb, wb);
  qkv_gemm<<<dim3(64, 8, 3), 256, 0, stream>>>(xb, wb, bq, bk, bv, qkv);
  flash_attn<<<1024, 256, 0, stream>>>(qkv, out);
}